// Round 12
// baseline (60.457 us; speedup 1.0000x reference)
//
#include <hip/hip_runtime.h>
#include <hip/hip_fp16.h>
#include <math.h>

#define N_NODES 50000
#define F_IN 32
#define DEG 32
#define BATCH 2048
#define NB_STRIDE 100  // ints per staged index row: 96 + 4 pad

typedef int int4v __attribute__((ext_vector_type(4)));
typedef unsigned int uint2v __attribute__((ext_vector_type(2)));
typedef unsigned int uint4v __attribute__((ext_vector_type(4)));
typedef float f32x2 __attribute__((ext_vector_type(2)));
typedef float f32x4 __attribute__((ext_vector_type(4)));

__device__ __forceinline__ void softmax3(float a0, float a1, float a2,
                                         float& w0, float& w1, float& w2) {
    float m = fmaxf(a0, fmaxf(a1, a2));
    float e0 = __expf(a0 - m), e1 = __expf(a1 - m), e2 = __expf(a2 - m);
    float s = 1.f / (e0 + e1 + e2);
    w0 = e0 * s; w1 = e1 * s; w2 = e2 * s;
}

__device__ __forceinline__ f32x2 shfl_xor_f2(f32x2 v, int m) {
    v.x = __shfl_xor(v.x, m, 64);
    v.y = __shfl_xor(v.y, m, 64);
    return v;
}

// ---- Kernel A: h0 = relu(feat @ w_mlp + b) -> fp8 table only. (unchanged)
__global__ __launch_bounds__(256) void mlp_kernel(
        const float* __restrict__ feat,
        const float* __restrict__ w,
        const float* __restrict__ b,
        const float* __restrict__ alpha1,
        const float* __restrict__ alpha2,
        float* __restrict__ sw1,    // 128*3
        float* __restrict__ sw2,    // 256*3
        unsigned char* __restrict__ h0q) {
    __shared__ float wl[F_IN * 64];
    __shared__ float fl[8 * F_IN];
    int tid = threadIdx.x;
    if (blockIdx.x == 0) {
        for (int q = tid; q < 384; q += 256) {
            const float* src = (q < 128) ? (alpha1 + q * 3) : (alpha2 + (q - 128) * 3);
            float* dst = (q < 128) ? (sw1 + q * 3) : (sw2 + (q - 128) * 3);
            float w0, w1, w2;
            softmax3(src[0], src[1], src[2], w0, w1, w2);
            dst[0] = w0; dst[1] = w1; dst[2] = w2;
        }
    }
    for (int i = tid; i < F_IN * 64; i += 256) wl[i] = w[i];
    int local = tid >> 5;        // node 0..7
    int f2 = (tid & 31) * 2;     // feature pair
    float b0 = b[f2], b1 = b[f2 + 1];
    const int noct = N_NODES / 8;  // 6250
    for (int q = blockIdx.x; q < noct; q += gridDim.x) {
        int n0 = q * 8;
        __syncthreads();
        fl[tid] = __builtin_nontemporal_load(feat + (size_t)n0 * F_IN + tid);
        __syncthreads();
        float a0 = b0, a1 = b1;
#pragma unroll
        for (int k = 0; k < F_IN; ++k) {
            float v = fl[local * F_IN + k];
            a0 = fmaf(v, wl[k * 64 + f2], a0);
            a1 = fmaf(v, wl[k * 64 + f2 + 1], a1);
        }
        a0 = fmaxf(a0, 0.f);
        a1 = fmaxf(a1, 0.f);
        int n = n0 + local;
        unsigned pk = __builtin_amdgcn_cvt_pk_fp8_f32(a0, a1, 0u, false);
        *reinterpret_cast<unsigned short*>(h0q + (size_t)n * 64 + f2) =
            (unsigned short)pk;
    }
}

// ---- Kernel B: layer-1 InterAgg, 16-B/lane gathers.
// 16 nodes / 256-thread block, 4 nodes per wave. Lane j: node m=j>>4,
// feature quarter q=j&3 (16 fp8 = 16 B of the 64-B row), row-group rg=(j>>2)&3.
// 16 rows per gather instruction (was 8) -> 6 gather instrs/node (was 12).
__global__ __launch_bounds__(256) void layer1_kernel(
        const int* __restrict__ adj,
        const unsigned char* __restrict__ h0q,
        const float* __restrict__ sw1,
        unsigned char* __restrict__ i1q) {
    __shared__ int nb[16 * NB_STRIDE];          // 6.4 KB
    __shared__ alignas(16) float swlT[6][64];   // [A r0..2 | B r0..2][feature]
    int tid = threadIdx.x;
    int n0 = blockIdx.x * 16;
    // transposed softmax-weight table
    for (int t = tid; t < 384; t += 256) {
        int p = t >> 6, f = t & 63;
        swlT[p][f] = (p < 3) ? sw1[f * 3 + p] : sw1[(64 + f) * 3 + (p - 3)];
    }
    // stage adj: 3 relations x 16 nodes x 32 deg = 384 int4
    for (int t = tid; t < 384; t += 256) {
        int r = t >> 7;
        int idx = t & 127;
        int m = idx >> 3;
        int d4 = (idx & 7) * 4;
        int4v v = __builtin_nontemporal_load(reinterpret_cast<const int4v*>(
                adj + ((size_t)r * N_NODES + (n0 + m)) * DEG + d4));
        *reinterpret_cast<int4v*>(&nb[m * NB_STRIDE + r * 32 + d4]) = v;
    }
    __syncthreads();
    int w = tid >> 6, j = tid & 63;
    int m = j >> 4;              // node in wave 0..3
    int q = j & 3;               // feature quarter
    int rg = (j >> 2) & 3;       // row group 0..3
    int nodeLocal = w * 4 + m;   // 0..15
    int n = n0 + nodeLocal;
    const int* nbrow = nb + nodeLocal * NB_STRIDE;
    const unsigned char* qb = h0q + 16 * q;
    f32x2 acc0[8] = {}, acc1[8] = {}, acc2[8] = {};
#pragma unroll
    for (int t = 0; t < 8; ++t) {
        unsigned row = (unsigned)nbrow[rg + 4 * t];
        uint4v d = *reinterpret_cast<const uint4v*>(qb + (size_t)(row * 64u));
        acc0[0] += __builtin_amdgcn_cvt_pk_f32_fp8(d.x, false);
        acc0[1] += __builtin_amdgcn_cvt_pk_f32_fp8(d.x, true);
        acc0[2] += __builtin_amdgcn_cvt_pk_f32_fp8(d.y, false);
        acc0[3] += __builtin_amdgcn_cvt_pk_f32_fp8(d.y, true);
        acc0[4] += __builtin_amdgcn_cvt_pk_f32_fp8(d.z, false);
        acc0[5] += __builtin_amdgcn_cvt_pk_f32_fp8(d.z, true);
        acc0[6] += __builtin_amdgcn_cvt_pk_f32_fp8(d.w, false);
        acc0[7] += __builtin_amdgcn_cvt_pk_f32_fp8(d.w, true);
    }
#pragma unroll
    for (int t = 0; t < 8; ++t) {
        unsigned row = (unsigned)nbrow[32 + rg + 4 * t];
        uint4v d = *reinterpret_cast<const uint4v*>(qb + (size_t)(row * 64u));
        acc1[0] += __builtin_amdgcn_cvt_pk_f32_fp8(d.x, false);
        acc1[1] += __builtin_amdgcn_cvt_pk_f32_fp8(d.x, true);
        acc1[2] += __builtin_amdgcn_cvt_pk_f32_fp8(d.y, false);
        acc1[3] += __builtin_amdgcn_cvt_pk_f32_fp8(d.y, true);
        acc1[4] += __builtin_amdgcn_cvt_pk_f32_fp8(d.z, false);
        acc1[5] += __builtin_amdgcn_cvt_pk_f32_fp8(d.z, true);
        acc1[6] += __builtin_amdgcn_cvt_pk_f32_fp8(d.w, false);
        acc1[7] += __builtin_amdgcn_cvt_pk_f32_fp8(d.w, true);
    }
#pragma unroll
    for (int t = 0; t < 8; ++t) {
        unsigned row = (unsigned)nbrow[64 + rg + 4 * t];
        uint4v d = *reinterpret_cast<const uint4v*>(qb + (size_t)(row * 64u));
        acc2[0] += __builtin_amdgcn_cvt_pk_f32_fp8(d.x, false);
        acc2[1] += __builtin_amdgcn_cvt_pk_f32_fp8(d.x, true);
        acc2[2] += __builtin_amdgcn_cvt_pk_f32_fp8(d.y, false);
        acc2[3] += __builtin_amdgcn_cvt_pk_f32_fp8(d.y, true);
        acc2[4] += __builtin_amdgcn_cvt_pk_f32_fp8(d.z, false);
        acc2[5] += __builtin_amdgcn_cvt_pk_f32_fp8(d.z, true);
        acc2[6] += __builtin_amdgcn_cvt_pk_f32_fp8(d.w, false);
        acc2[7] += __builtin_amdgcn_cvt_pk_f32_fp8(d.w, true);
    }
    // combine the 4 row-groups (lane bits 2,3)
#pragma unroll
    for (int mm = 4; mm <= 8; mm <<= 1) {
#pragma unroll
        for (int k = 0; k < 8; ++k) {
            acc0[k] += shfl_xor_f2(acc0[k], mm);
            acc1[k] += shfl_xor_f2(acc1[k], mm);
            acc2[k] += shfl_xor_f2(acc2[k], mm);
        }
    }
    // self row (16 features of this quarter)
    uint4v sd = *reinterpret_cast<const uint4v*>(qb + (size_t)((unsigned)n * 64u));
    unsigned sdw[4] = {sd.x, sd.y, sd.z, sd.w};
    const float inv = 1.f / 32.f;
    uint4v ua, ub;
    unsigned uaw[4], ubw[4];
#pragma unroll
    for (int c = 0; c < 4; ++c) {
        int fb = 16 * q + 4 * c;
        f32x4 wa0 = *reinterpret_cast<const f32x4*>(&swlT[0][fb]);
        f32x4 wa1 = *reinterpret_cast<const f32x4*>(&swlT[1][fb]);
        f32x4 wa2 = *reinterpret_cast<const f32x4*>(&swlT[2][fb]);
        f32x4 wb0 = *reinterpret_cast<const f32x4*>(&swlT[3][fb]);
        f32x4 wb1 = *reinterpret_cast<const f32x4*>(&swlT[4][fb]);
        f32x4 wb2 = *reinterpret_cast<const f32x4*>(&swlT[5][fb]);
        f32x2 slo = __builtin_amdgcn_cvt_pk_f32_fp8(sdw[c], false);
        f32x2 shi = __builtin_amdgcn_cvt_pk_f32_fp8(sdw[c], true);
        float sv[4] = {slo.x, slo.y, shi.x, shi.y};
        float oa[4], ob[4];
#pragma unroll
        for (int k = 0; k < 4; ++k) {
            int i = 4 * c + k;
            float a0 = acc0[i >> 1][i & 1] * inv;
            float a1 = acc1[i >> 1][i & 1] * inv;
            float a2 = acc2[i >> 1][i & 1] * inv;
            float s = sv[k];
            oa[k] = wa0[k] * a0 + wa1[k] * a1 + wa2[k] * a2;
            ob[k] = wb0[k] * (s - a0) + wb1[k] * (s - a1) + wb2[k] * (s - a2);
        }
        unsigned u = __builtin_amdgcn_cvt_pk_fp8_f32(oa[0], oa[1], 0u, false);
        uaw[c] = __builtin_amdgcn_cvt_pk_fp8_f32(oa[2], oa[3], u, true);
        u = __builtin_amdgcn_cvt_pk_fp8_f32(ob[0], ob[1], 0u, false);
        ubw[c] = __builtin_amdgcn_cvt_pk_fp8_f32(ob[2], ob[3], u, true);
    }
    ua.x = uaw[0]; ua.y = uaw[1]; ua.z = uaw[2]; ua.w = uaw[3];
    ub.x = ubw[0]; ub.y = ubw[1]; ub.z = ubw[2]; ub.w = ubw[3];
    if (rg == 0) {
        __builtin_nontemporal_store(ua,
            reinterpret_cast<uint4v*>(i1q + (size_t)n * 128 + 16 * q));
    } else if (rg == 1) {
        __builtin_nontemporal_store(ub,
            reinterpret_cast<uint4v*>(i1q + (size_t)n * 128 + 64 + 16 * q));
    }
}

// ---- Kernel C: layer-2 InterAgg + fused dense head. (unchanged from r11)
__global__ __launch_bounds__(256) void layer2_kernel(
        const int* __restrict__ nodes,
        const int* __restrict__ adj,
        const unsigned char* __restrict__ h0q,
        const unsigned char* __restrict__ i1q,
        const float* __restrict__ sw2,
        const float* __restrict__ w_d2,
        const float* __restrict__ b_d2,
        const float* __restrict__ w_d1,
        const float* __restrict__ b_d1,
        const float* __restrict__ prior,
        float* __restrict__ out) {
    __shared__ int nb[4][96];
    __shared__ int nid[4];
    __shared__ float swl[768];  // wA(384) | wB(384)
    int tid = threadIdx.x;
    int b0 = blockIdx.x * 4;
    if (tid < 4) nid[tid] = nodes[b0 + tid];
    if (tid >= 64 && tid < 256) {
        int q = tid - 64;
        reinterpret_cast<float4*>(swl)[q] = reinterpret_cast<const float4*>(sw2)[q];
    }
    __syncthreads();
    if (tid < 96) {
        int local = tid / 24, rem = tid - local * 24;
        int r = rem >> 3, d4 = (rem & 7) * 4;
        int4v v = __builtin_nontemporal_load(reinterpret_cast<const int4v*>(
                adj + ((size_t)r * N_NODES + nid[local]) * DEG + d4));
        *reinterpret_cast<int4v*>(&nb[local][r * 32 + d4]) = v;
    }
    __syncthreads();
    int local = tid >> 6, j = tid & 63;
    int bb = b0 + local;
    int n = nid[local];
    int g = j >> 4, e = j & 15;
    int idxs[24];
#pragma unroll
    for (int t = 0; t < 24; ++t) idxs[t] = nb[local][t * 4 + g];
    const unsigned char* qbase = i1q + 8 * e;
    f32x2 acc0[4] = {}, acc1[4] = {}, acc2[4] = {};
#pragma unroll
    for (int t = 0; t < 8; ++t) {
        uint2v d = *reinterpret_cast<const uint2v*>(
            qbase + (size_t)((unsigned)idxs[t] * 128u));
        acc0[0] += __builtin_amdgcn_cvt_pk_f32_fp8(d.x, false);
        acc0[1] += __builtin_amdgcn_cvt_pk_f32_fp8(d.x, true);
        acc0[2] += __builtin_amdgcn_cvt_pk_f32_fp8(d.y, false);
        acc0[3] += __builtin_amdgcn_cvt_pk_f32_fp8(d.y, true);
    }
#pragma unroll
    for (int t = 8; t < 16; ++t) {
        uint2v d = *reinterpret_cast<const uint2v*>(
            qbase + (size_t)((unsigned)idxs[t] * 128u));
        acc1[0] += __builtin_amdgcn_cvt_pk_f32_fp8(d.x, false);
        acc1[1] += __builtin_amdgcn_cvt_pk_f32_fp8(d.x, true);
        acc1[2] += __builtin_amdgcn_cvt_pk_f32_fp8(d.y, false);
        acc1[3] += __builtin_amdgcn_cvt_pk_f32_fp8(d.y, true);
    }
#pragma unroll
    for (int t = 16; t < 24; ++t) {
        uint2v d = *reinterpret_cast<const uint2v*>(
            qbase + (size_t)((unsigned)idxs[t] * 128u));
        acc2[0] += __builtin_amdgcn_cvt_pk_f32_fp8(d.x, false);
        acc2[1] += __builtin_amdgcn_cvt_pk_f32_fp8(d.x, true);
        acc2[2] += __builtin_amdgcn_cvt_pk_f32_fp8(d.y, false);
        acc2[3] += __builtin_amdgcn_cvt_pk_f32_fp8(d.y, true);
    }
#pragma unroll
    for (int mm = 16; mm <= 32; mm <<= 1) {
#pragma unroll
        for (int q = 0; q < 4; ++q) {
            acc0[q] += shfl_xor_f2(acc0[q], mm);
            acc1[q] += shfl_xor_f2(acc1[q], mm);
            acc2[q] += shfl_xor_f2(acc2[q], mm);
        }
    }
    const float inv = 1.f / 32.f;
    float p0 = 0.f, p1 = 0.f;
    if (g == 0) {
        float sarr[8];
        {
            uint2v sd = *reinterpret_cast<const uint2v*>(
                qbase + (size_t)((unsigned)n * 128u));
            f32x2 s0 = __builtin_amdgcn_cvt_pk_f32_fp8(sd.x, false);
            f32x2 s1 = __builtin_amdgcn_cvt_pk_f32_fp8(sd.x, true);
            f32x2 s2 = __builtin_amdgcn_cvt_pk_f32_fp8(sd.y, false);
            f32x2 s3 = __builtin_amdgcn_cvt_pk_f32_fp8(sd.y, true);
            sarr[0] = s0.x; sarr[1] = s0.y; sarr[2] = s1.x; sarr[3] = s1.y;
            sarr[4] = s2.x; sarr[5] = s2.y; sarr[6] = s3.x; sarr[7] = s3.y;
        }
        const float* wa = swl + 24 * e;
        const float* wb = swl + 384 + 24 * e;
#pragma unroll
        for (int i = 0; i < 8; ++i) {
            int f = 8 * e + i;
            float a0 = acc0[i >> 1][i & 1] * inv;
            float a1 = acc1[i >> 1][i & 1] * inv;
            float a2 = acc2[i >> 1][i & 1] * inv;
            float s = sarr[i];
            float i2a = wa[3 * i] * a0 + wa[3 * i + 1] * a1 + wa[3 * i + 2] * a2;
            float i2b = wb[3 * i] * (s - a0) + wb[3 * i + 1] * (s - a1) +
                        wb[3 * i + 2] * (s - a2);
            p0 += i2a * w_d2[(192 + f) * 2 + 0] + i2b * w_d2[(320 + f) * 2 + 0];
            p1 += i2a * w_d2[(192 + f) * 2 + 1] + i2b * w_d2[(320 + f) * 2 + 1];
        }
    } else if (g == 1) {
        unsigned d = *reinterpret_cast<const unsigned*>(h0q + (size_t)n * 64 + 4 * e);
        f32x2 lo = __builtin_amdgcn_cvt_pk_f32_fp8(d, false);
        f32x2 hi = __builtin_amdgcn_cvt_pk_f32_fp8(d, true);
        float sv[4] = {lo.x, lo.y, hi.x, hi.y};
#pragma unroll
        for (int i = 0; i < 4; ++i) {
            int f = 4 * e + i;
            p0 += sv[i] * w_d2[f * 2 + 0];
            p1 += sv[i] * w_d2[f * 2 + 1];
        }
    } else if (g == 2) {
        float sarr[8];
        {
            uint2v sd = *reinterpret_cast<const uint2v*>(
                qbase + (size_t)((unsigned)n * 128u));
            f32x2 s0 = __builtin_amdgcn_cvt_pk_f32_fp8(sd.x, false);
            f32x2 s1 = __builtin_amdgcn_cvt_pk_f32_fp8(sd.x, true);
            f32x2 s2 = __builtin_amdgcn_cvt_pk_f32_fp8(sd.y, false);
            f32x2 s3 = __builtin_amdgcn_cvt_pk_f32_fp8(sd.y, true);
            sarr[0] = s0.x; sarr[1] = s0.y; sarr[2] = s1.x; sarr[3] = s1.y;
            sarr[4] = s2.x; sarr[5] = s2.y; sarr[6] = s3.x; sarr[7] = s3.y;
        }
#pragma unroll
        for (int i = 0; i < 8; ++i) {
            int f = 8 * e + i;
            p0 += sarr[i] * w_d2[(64 + f) * 2 + 0];
            p1 += sarr[i] * w_d2[(64 + f) * 2 + 1];
        }
    }
#pragma unroll
    for (int mm = 1; mm <= 32; mm <<= 1) {
        p0 += __shfl_xor(p0, mm, 64);
        p1 += __shfl_xor(p1, mm, 64);
    }
    if (j == 0) {
        float x0 = p0 + b_d2[0], x1 = p1 + b_d2[1];
        x0 = x0 > 0.f ? x0 : 0.3f * x0;
        x1 = x1 > 0.f ? x1 : 0.3f * x1;
        x0 += __logf(prior[0]);
        x1 += __logf(prior[1]);
        float z = x0 * w_d1[0] + x1 * w_d1[1] + b_d1[0];
        out[bb] = 1.f / (1.f + __expf(-z));
    }
}

extern "C" void kernel_launch(void* const* d_in, const int* in_sizes, int n_in,
                              void* d_out, int out_size, void* d_ws, size_t ws_size,
                              hipStream_t stream) {
    const int*   nodes  = (const int*)d_in[0];
    const float* feat   = (const float*)d_in[1];
    const int*   adj    = (const int*)d_in[2];
    const float* prior  = (const float*)d_in[3];
    const float* w_mlp  = (const float*)d_in[4];
    const float* b_mlp  = (const float*)d_in[5];
    const float* alpha1 = (const float*)d_in[6];
    const float* alpha2 = (const float*)d_in[7];
    const float* w_d2   = (const float*)d_in[8];
    const float* b_d2   = (const float*)d_in[9];
    const float* w_d1   = (const float*)d_in[10];
    const float* b_d1   = (const float*)d_in[11];
    float* out = (float*)d_out;

    // ws: sw1(384f) | sw2(768f) | pad->8192 | h0q fp8 N*64 (3.2MB) |
    //     i1q fp8 N*128 (6.4MB)
    float* sw1 = (float*)d_ws;
    float* sw2 = sw1 + 128 * 3;
    unsigned char* h0q = (unsigned char*)((char*)d_ws + 8192);
    unsigned char* i1q = h0q + (size_t)N_NODES * 64;

    mlp_kernel<<<2048, 256, 0, stream>>>(feat, w_mlp, b_mlp, alpha1, alpha2,
                                         sw1, sw2, h0q);
    layer1_kernel<<<N_NODES / 16, 256, 0, stream>>>(adj, h0q, sw1, i1q);
    layer2_kernel<<<BATCH / 4, 256, 0, stream>>>(nodes, adj, h0q, i1q, sw2,
                                                 w_d2, b_d2, w_d1, b_d1, prior, out);
}

// Round 13
// 55.098 us; speedup vs baseline: 1.0972x; 1.0972x over previous
//
#include <hip/hip_runtime.h>
#include <hip/hip_fp16.h>
#include <math.h>

#define N_NODES 50000
#define F_IN 32
#define DEG 32
#define BATCH 2048
#define NB_STRIDE 100  // ints per staged index row: 96 + 4 pad

typedef int int4v __attribute__((ext_vector_type(4)));
typedef unsigned int uint2v __attribute__((ext_vector_type(2)));
typedef float f32x2 __attribute__((ext_vector_type(2)));

__device__ __forceinline__ void softmax3(float a0, float a1, float a2,
                                         float& w0, float& w1, float& w2) {
    float m = fmaxf(a0, fmaxf(a1, a2));
    float e0 = __expf(a0 - m), e1 = __expf(a1 - m), e2 = __expf(a2 - m);
    float s = 1.f / (e0 + e1 + e2);
    w0 = e0 * s; w1 = e1 * s; w2 = e2 * s;
}

__device__ __forceinline__ f32x2 shfl_xor_f2(f32x2 v, int m) {
    v.x = __shfl_xor(v.x, m, 64);
    v.y = __shfl_xor(v.y, m, 64);
    return v;
}

// ---- Kernel A: h0 = relu(feat @ w_mlp + b) -> fp8 table only.
// 8 nodes / 256-thread block, 2 features per thread. Grid-strided.
__global__ __launch_bounds__(256) void mlp_kernel(
        const float* __restrict__ feat,
        const float* __restrict__ w,
        const float* __restrict__ b,
        const float* __restrict__ alpha1,
        const float* __restrict__ alpha2,
        float* __restrict__ sw1,    // 128*3
        float* __restrict__ sw2,    // 256*3
        unsigned char* __restrict__ h0q) {
    __shared__ float wl[F_IN * 64];
    __shared__ float fl[8 * F_IN];
    int tid = threadIdx.x;
    if (blockIdx.x == 0) {
        for (int q = tid; q < 384; q += 256) {
            const float* src = (q < 128) ? (alpha1 + q * 3) : (alpha2 + (q - 128) * 3);
            float* dst = (q < 128) ? (sw1 + q * 3) : (sw2 + (q - 128) * 3);
            float w0, w1, w2;
            softmax3(src[0], src[1], src[2], w0, w1, w2);
            dst[0] = w0; dst[1] = w1; dst[2] = w2;
        }
    }
    for (int i = tid; i < F_IN * 64; i += 256) wl[i] = w[i];
    int local = tid >> 5;        // node 0..7
    int f2 = (tid & 31) * 2;     // feature pair
    float b0 = b[f2], b1 = b[f2 + 1];
    const int noct = N_NODES / 8;  // 6250
    for (int q = blockIdx.x; q < noct; q += gridDim.x) {
        int n0 = q * 8;
        __syncthreads();  // protect fl from previous iteration's readers
        fl[tid] = __builtin_nontemporal_load(feat + (size_t)n0 * F_IN + tid);
        __syncthreads();
        float a0 = b0, a1 = b1;
#pragma unroll
        for (int k = 0; k < F_IN; ++k) {
            float v = fl[local * F_IN + k];
            a0 = fmaf(v, wl[k * 64 + f2], a0);
            a1 = fmaf(v, wl[k * 64 + f2 + 1], a1);
        }
        a0 = fmaxf(a0, 0.f);
        a1 = fmaxf(a1, 0.f);
        int n = n0 + local;
        unsigned pk = __builtin_amdgcn_cvt_pk_fp8_f32(a0, a1, 0u, false);
        *reinterpret_cast<unsigned short*>(h0q + (size_t)n * 64 + f2) =
            (unsigned short)pk;
    }
}

// ---- Kernel B: layer-1 InterAgg. 16 nodes / 128-thread block, 8 nodes/wave,
// lane = (node, octet). All reads from fp8 h0q (L2-resident 3.2 MB).
__global__ __launch_bounds__(128) void layer1_kernel(
        const int* __restrict__ adj,
        const unsigned char* __restrict__ h0q,
        const float* __restrict__ sw1,
        unsigned char* __restrict__ i1q) {
    __shared__ int nb[16 * NB_STRIDE];  // 6.4 KB
    __shared__ float swl[384];          // wA(192) | wB(192)
    int tid = threadIdx.x;
    int n0 = blockIdx.x * 16;
    if (tid < 96)
        reinterpret_cast<float4*>(swl)[tid] = reinterpret_cast<const float4*>(sw1)[tid];
    // stage adj: 3 relations x 16 nodes x 32 deg = 384 int4, 3 per lane
#pragma unroll
    for (int q = tid; q < 384; q += 128) {
        int r = q >> 7;            // 0..2
        int idx = q & 127;
        int m = idx >> 3;          // node local 0..15
        int d4 = (idx & 7) * 4;
        int4v v = __builtin_nontemporal_load(reinterpret_cast<const int4v*>(
                adj + ((size_t)r * N_NODES + (n0 + m)) * DEG + d4));
        *reinterpret_cast<int4v*>(&nb[m * NB_STRIDE + r * 32 + d4]) = v;
    }
    __syncthreads();
    int w = tid >> 6, j = tid & 63;
    int m = w * 8 + (j >> 3);      // node local 0..15
    int e = j & 7;                 // feature octet
    int n = n0 + m;
    const int* nbrow = nb + m * NB_STRIDE;
    const unsigned char* qb = h0q + 8 * e;
    f32x2 acc0[4] = {}, acc1[4] = {}, acc2[4] = {};
#pragma unroll 8
    for (int t = 0; t < 32; ++t) {
        uint2v d = *reinterpret_cast<const uint2v*>(qb + (size_t)((unsigned)nbrow[t] * 64u));
        acc0[0] += __builtin_amdgcn_cvt_pk_f32_fp8(d.x, false);
        acc0[1] += __builtin_amdgcn_cvt_pk_f32_fp8(d.x, true);
        acc0[2] += __builtin_amdgcn_cvt_pk_f32_fp8(d.y, false);
        acc0[3] += __builtin_amdgcn_cvt_pk_f32_fp8(d.y, true);
    }
#pragma unroll 8
    for (int t = 32; t < 64; ++t) {
        uint2v d = *reinterpret_cast<const uint2v*>(qb + (size_t)((unsigned)nbrow[t] * 64u));
        acc1[0] += __builtin_amdgcn_cvt_pk_f32_fp8(d.x, false);
        acc1[1] += __builtin_amdgcn_cvt_pk_f32_fp8(d.x, true);
        acc1[2] += __builtin_amdgcn_cvt_pk_f32_fp8(d.y, false);
        acc1[3] += __builtin_amdgcn_cvt_pk_f32_fp8(d.y, true);
    }
#pragma unroll 8
    for (int t = 64; t < 96; ++t) {
        uint2v d = *reinterpret_cast<const uint2v*>(qb + (size_t)((unsigned)nbrow[t] * 64u));
        acc2[0] += __builtin_amdgcn_cvt_pk_f32_fp8(d.x, false);
        acc2[1] += __builtin_amdgcn_cvt_pk_f32_fp8(d.x, true);
        acc2[2] += __builtin_amdgcn_cvt_pk_f32_fp8(d.y, false);
        acc2[3] += __builtin_amdgcn_cvt_pk_f32_fp8(d.y, true);
    }

    // self row from fp8 (same byte layout as gathers)
    float sarr[8];
    {
        uint2v sd = *reinterpret_cast<const uint2v*>(qb + (size_t)((unsigned)n * 64u));
        f32x2 s0 = __builtin_amdgcn_cvt_pk_f32_fp8(sd.x, false);
        f32x2 s1 = __builtin_amdgcn_cvt_pk_f32_fp8(sd.x, true);
        f32x2 s2 = __builtin_amdgcn_cvt_pk_f32_fp8(sd.y, false);
        f32x2 s3 = __builtin_amdgcn_cvt_pk_f32_fp8(sd.y, true);
        sarr[0] = s0.x; sarr[1] = s0.y; sarr[2] = s1.x; sarr[3] = s1.y;
        sarr[4] = s2.x; sarr[5] = s2.y; sarr[6] = s3.x; sarr[7] = s3.y;
    }
    float wA[24], wB[24];
    {
        const float4* pa = reinterpret_cast<const float4*>(swl + 24 * e);
        const float4* pb = reinterpret_cast<const float4*>(swl + 192 + 24 * e);
#pragma unroll
        for (int q = 0; q < 6; ++q) {
            float4 ta = pa[q], tb = pb[q];
            wA[4 * q] = ta.x; wA[4 * q + 1] = ta.y; wA[4 * q + 2] = ta.z; wA[4 * q + 3] = ta.w;
            wB[4 * q] = tb.x; wB[4 * q + 1] = tb.y; wB[4 * q + 2] = tb.z; wB[4 * q + 3] = tb.w;
        }
    }
    const float inv = 1.f / 32.f;
    float oa[8], ob[8];
#pragma unroll
    for (int i = 0; i < 8; ++i) {
        float a0 = acc0[i >> 1][i & 1] * inv;
        float a1 = acc1[i >> 1][i & 1] * inv;
        float a2 = acc2[i >> 1][i & 1] * inv;
        float s = sarr[i];
        oa[i] = wA[3 * i] * a0 + wA[3 * i + 1] * a1 + wA[3 * i + 2] * a2;
        ob[i] = wB[3 * i] * (s - a0) + wB[3 * i + 1] * (s - a1) + wB[3 * i + 2] * (s - a2);
    }
    unsigned qa0 = __builtin_amdgcn_cvt_pk_fp8_f32(oa[0], oa[1], 0u, false);
    qa0 = __builtin_amdgcn_cvt_pk_fp8_f32(oa[2], oa[3], qa0, true);
    unsigned qa1 = __builtin_amdgcn_cvt_pk_fp8_f32(oa[4], oa[5], 0u, false);
    qa1 = __builtin_amdgcn_cvt_pk_fp8_f32(oa[6], oa[7], qa1, true);
    uint2v ua = {qa0, qa1};
    __builtin_nontemporal_store(ua,
        reinterpret_cast<uint2v*>(i1q + (size_t)n * 128 + 8 * e));
    unsigned qb0 = __builtin_amdgcn_cvt_pk_fp8_f32(ob[0], ob[1], 0u, false);
    qb0 = __builtin_amdgcn_cvt_pk_fp8_f32(ob[2], ob[3], qb0, true);
    unsigned qb1 = __builtin_amdgcn_cvt_pk_fp8_f32(ob[4], ob[5], 0u, false);
    qb1 = __builtin_amdgcn_cvt_pk_fp8_f32(ob[6], ob[7], qb1, true);
    uint2v ub = {qb0, qb1};
    __builtin_nontemporal_store(ub,
        reinterpret_cast<uint2v*>(i1q + (size_t)n * 128 + 64 + 8 * e));
}

// ---- Kernel C: layer-2 InterAgg + fused dense head.
// 4 batch nodes / 256-thread block, one wave per node. All fp8 reads.
__global__ __launch_bounds__(256) void layer2_kernel(
        const int* __restrict__ nodes,
        const int* __restrict__ adj,
        const unsigned char* __restrict__ h0q,
        const unsigned char* __restrict__ i1q,
        const float* __restrict__ sw2,
        const float* __restrict__ w_d2,
        const float* __restrict__ b_d2,
        const float* __restrict__ w_d1,
        const float* __restrict__ b_d1,
        const float* __restrict__ prior,
        float* __restrict__ out) {
    __shared__ int nb[4][96];
    __shared__ int nid[4];
    __shared__ float swl[768];  // wA(384) | wB(384)
    int tid = threadIdx.x;
    int b0 = blockIdx.x * 4;
    if (tid < 4) nid[tid] = nodes[b0 + tid];
    if (tid >= 64 && tid < 256) {
        int q = tid - 64;
        reinterpret_cast<float4*>(swl)[q] = reinterpret_cast<const float4*>(sw2)[q];
    }
    __syncthreads();
    if (tid < 96) {
        int local = tid / 24, rem = tid - local * 24;
        int r = rem >> 3, d4 = (rem & 7) * 4;
        int4v v = __builtin_nontemporal_load(reinterpret_cast<const int4v*>(
                adj + ((size_t)r * N_NODES + nid[local]) * DEG + d4));
        *reinterpret_cast<int4v*>(&nb[local][r * 32 + d4]) = v;
    }
    __syncthreads();
    int local = tid >> 6, j = tid & 63;
    int bb = b0 + local;
    int n = nid[local];
    int g = j >> 4, e = j & 15;
    int idxs[24];
#pragma unroll
    for (int t = 0; t < 24; ++t) idxs[t] = nb[local][t * 4 + g];
    const unsigned char* qbase = i1q + 8 * e;
    f32x2 acc0[4] = {}, acc1[4] = {}, acc2[4] = {};
#pragma unroll
    for (int t = 0; t < 8; ++t) {
        uint2v d = *reinterpret_cast<const uint2v*>(
            qbase + (size_t)((unsigned)idxs[t] * 128u));
        acc0[0] += __builtin_amdgcn_cvt_pk_f32_fp8(d.x, false);
        acc0[1] += __builtin_amdgcn_cvt_pk_f32_fp8(d.x, true);
        acc0[2] += __builtin_amdgcn_cvt_pk_f32_fp8(d.y, false);
        acc0[3] += __builtin_amdgcn_cvt_pk_f32_fp8(d.y, true);
    }
#pragma unroll
    for (int t = 8; t < 16; ++t) {
        uint2v d = *reinterpret_cast<const uint2v*>(
            qbase + (size_t)((unsigned)idxs[t] * 128u));
        acc1[0] += __builtin_amdgcn_cvt_pk_f32_fp8(d.x, false);
        acc1[1] += __builtin_amdgcn_cvt_pk_f32_fp8(d.x, true);
        acc1[2] += __builtin_amdgcn_cvt_pk_f32_fp8(d.y, false);
        acc1[3] += __builtin_amdgcn_cvt_pk_f32_fp8(d.y, true);
    }
#pragma unroll
    for (int t = 16; t < 24; ++t) {
        uint2v d = *reinterpret_cast<const uint2v*>(
            qbase + (size_t)((unsigned)idxs[t] * 128u));
        acc2[0] += __builtin_amdgcn_cvt_pk_f32_fp8(d.x, false);
        acc2[1] += __builtin_amdgcn_cvt_pk_f32_fp8(d.x, true);
        acc2[2] += __builtin_amdgcn_cvt_pk_f32_fp8(d.y, false);
        acc2[3] += __builtin_amdgcn_cvt_pk_f32_fp8(d.y, true);
    }
#pragma unroll
    for (int mm = 16; mm <= 32; mm <<= 1) {
#pragma unroll
        for (int q = 0; q < 4; ++q) {
            acc0[q] += shfl_xor_f2(acc0[q], mm);
            acc1[q] += shfl_xor_f2(acc1[q], mm);
            acc2[q] += shfl_xor_f2(acc2[q], mm);
        }
    }
    const float inv = 1.f / 32.f;
    float p0 = 0.f, p1 = 0.f;
    if (g == 0) {
        // inter2 for features f=8e..8e+7; self i1 row from fp8
        float sarr[8];
        {
            uint2v sd = *reinterpret_cast<const uint2v*>(
                qbase + (size_t)((unsigned)n * 128u));
            f32x2 s0 = __builtin_amdgcn_cvt_pk_f32_fp8(sd.x, false);
            f32x2 s1 = __builtin_amdgcn_cvt_pk_f32_fp8(sd.x, true);
            f32x2 s2 = __builtin_amdgcn_cvt_pk_f32_fp8(sd.y, false);
            f32x2 s3 = __builtin_amdgcn_cvt_pk_f32_fp8(sd.y, true);
            sarr[0] = s0.x; sarr[1] = s0.y; sarr[2] = s1.x; sarr[3] = s1.y;
            sarr[4] = s2.x; sarr[5] = s2.y; sarr[6] = s3.x; sarr[7] = s3.y;
        }
        const float* wa = swl + 24 * e;
        const float* wb = swl + 384 + 24 * e;
#pragma unroll
        for (int i = 0; i < 8; ++i) {
            int f = 8 * e + i;
            float a0 = acc0[i >> 1][i & 1] * inv;
            float a1 = acc1[i >> 1][i & 1] * inv;
            float a2 = acc2[i >> 1][i & 1] * inv;
            float s = sarr[i];
            float i2a = wa[3 * i] * a0 + wa[3 * i + 1] * a1 + wa[3 * i + 2] * a2;
            float i2b = wb[3 * i] * (s - a0) + wb[3 * i + 1] * (s - a1) +
                        wb[3 * i + 2] * (s - a2);
            p0 += i2a * w_d2[(192 + f) * 2 + 0] + i2b * w_d2[(320 + f) * 2 + 0];
            p1 += i2a * w_d2[(192 + f) * 2 + 1] + i2b * w_d2[(320 + f) * 2 + 1];
        }
    } else if (g == 1) {
        // self h0 features 4e..4e+3 from fp8
        unsigned d = *reinterpret_cast<const unsigned*>(h0q + (size_t)n * 64 + 4 * e);
        f32x2 lo = __builtin_amdgcn_cvt_pk_f32_fp8(d, false);
        f32x2 hi = __builtin_amdgcn_cvt_pk_f32_fp8(d, true);
        float sv[4] = {lo.x, lo.y, hi.x, hi.y};
#pragma unroll
        for (int i = 0; i < 4; ++i) {
            int f = 4 * e + i;
            p0 += sv[i] * w_d2[f * 2 + 0];
            p1 += sv[i] * w_d2[f * 2 + 1];
        }
    } else if (g == 2) {
        // self inter1 features 8e..8e+7 from fp8 -> w_d2 rows 64+f
        float sarr[8];
        {
            uint2v sd = *reinterpret_cast<const uint2v*>(
                qbase + (size_t)((unsigned)n * 128u));
            f32x2 s0 = __builtin_amdgcn_cvt_pk_f32_fp8(sd.x, false);
            f32x2 s1 = __builtin_amdgcn_cvt_pk_f32_fp8(sd.x, true);
            f32x2 s2 = __builtin_amdgcn_cvt_pk_f32_fp8(sd.y, false);
            f32x2 s3 = __builtin_amdgcn_cvt_pk_f32_fp8(sd.y, true);
            sarr[0] = s0.x; sarr[1] = s0.y; sarr[2] = s1.x; sarr[3] = s1.y;
            sarr[4] = s2.x; sarr[5] = s2.y; sarr[6] = s3.x; sarr[7] = s3.y;
        }
#pragma unroll
        for (int i = 0; i < 8; ++i) {
            int f = 8 * e + i;
            p0 += sarr[i] * w_d2[(64 + f) * 2 + 0];
            p1 += sarr[i] * w_d2[(64 + f) * 2 + 1];
        }
    }
#pragma unroll
    for (int mm = 1; mm <= 32; mm <<= 1) {
        p0 += __shfl_xor(p0, mm, 64);
        p1 += __shfl_xor(p1, mm, 64);
    }
    if (j == 0) {
        float x0 = p0 + b_d2[0], x1 = p1 + b_d2[1];
        x0 = x0 > 0.f ? x0 : 0.3f * x0;
        x1 = x1 > 0.f ? x1 : 0.3f * x1;
        x0 += __logf(prior[0]);
        x1 += __logf(prior[1]);
        float z = x0 * w_d1[0] + x1 * w_d1[1] + b_d1[0];
        out[bb] = 1.f / (1.f + __expf(-z));
    }
}

extern "C" void kernel_launch(void* const* d_in, const int* in_sizes, int n_in,
                              void* d_out, int out_size, void* d_ws, size_t ws_size,
                              hipStream_t stream) {
    const int*   nodes  = (const int*)d_in[0];
    const float* feat   = (const float*)d_in[1];
    const int*   adj    = (const int*)d_in[2];
    const float* prior  = (const float*)d_in[3];
    const float* w_mlp  = (const float*)d_in[4];
    const float* b_mlp  = (const float*)d_in[5];
    const float* alpha1 = (const float*)d_in[6];
    const float* alpha2 = (const float*)d_in[7];
    const float* w_d2   = (const float*)d_in[8];
    const float* b_d2   = (const float*)d_in[9];
    const float* w_d1   = (const float*)d_in[10];
    const float* b_d1   = (const float*)d_in[11];
    float* out = (float*)d_out;

    // ws: sw1(384f) | sw2(768f) | pad->8192 | h0q fp8 N*64 (3.2MB) |
    //     i1q fp8 N*128 (6.4MB)
    float* sw1 = (float*)d_ws;
    float* sw2 = sw1 + 128 * 3;
    unsigned char* h0q = (unsigned char*)((char*)d_ws + 8192);
    unsigned char* i1q = h0q + (size_t)N_NODES * 64;

    mlp_kernel<<<2048, 256, 0, stream>>>(feat, w_mlp, b_mlp, alpha1, alpha2,
                                         sw1, sw2, h0q);
    layer1_kernel<<<N_NODES / 16, 128, 0, stream>>>(adj, h0q, sw1, i1q);
    layer2_kernel<<<BATCH / 4, 256, 0, stream>>>(nodes, adj, h0q, i1q, sw2,
                                                 w_d2, b_d2, w_d1, b_d1, prior, out);
}